// Round 2
// baseline (474.304 us; speedup 1.0000x reference)
//
#include <hip/hip_runtime.h>
#include <utility>

// LocalGLMnet fused forward, v2: scratch-free by construction.
// interim = sigmoid(locally-connected 5x5), forecast = sum_i x*interim,
// penalty = 0.01*sum_i interim^2. B=16384, H=10, W=100, pad 2. Out (B,2,100) f32.
//
// v1 post-mortem: rolling-window + mod-5 slot indexing didn't fully unroll ->
// runtime-indexed arrays -> scratch (438 MB spill writes, 380 us). v2 streams
// input rows r=0..9 (row r feeds output rows i=r-2..r+2, tap row di=r+2-i)
// and unrolls EVERYTHING via integer_sequence folds: every array index is a
// compile-time constant, so nothing can go to local memory.

#define L2E 1.44269504088896340736f
constexpr int NB = 4;  // batches per thread

__device__ __forceinline__ float fast_sigmoid(float s) {
    float e = __builtin_amdgcn_exp2f(s * (-L2E));   // exp(-s)
    return __builtin_amdgcn_rcpf(1.0f + e);         // 1/(1+exp(-s))
}

template <class F, int... Is>
__device__ __forceinline__ void static_for(F&& f, std::integer_sequence<int, Is...>) {
    (f(std::integral_constant<int, Is>{}), ...);
}

__global__ __launch_bounds__(256, 3)
void glm_fused(const float* __restrict__ x, const float* __restrict__ w,
               float* __restrict__ out) {
    __shared__ float wl[12500];  // weight half-tile: [i][jl*25 + di*5 + c], jl in [0,50)

    const int tid = threadIdx.x;
    const int jh  = blockIdx.x & 1;   // j-half: 0 -> j 0..49, 1 -> j 50..99
    const int blk = blockIdx.x >> 1;

    // stage weight half-tile once (validated in v1)
    {
        const float2* __restrict__ src = (const float2*)w;
        float2* dst = (float2*)wl;
        for (int u = tid; u < 6250; u += 256) {
            int i  = u / 625;
            int r2 = u - i * 625;
            dst[i * 625 + r2] = src[i * 1250 + jh * 625 + r2];
        }
    }
    __syncthreads();

    const int tl = blk * 256 + tid;
    const int jl = tl % 50;
    const int bg = tl / 50;           // batch group (NB batches)
    const int j  = jh * 50 + jl;

    const float* __restrict__ xb = x + bg * (NB * 1000);

    int  ccol[5];
    bool cval[5];
#pragma unroll
    for (int c = 0; c < 5; ++c) {
        int col = j - 2 + c;
        cval[c] = (unsigned)col < 100u;
        ccol[c] = cval[c] ? col : 0;
    }

    float s[NB][10];
#pragma unroll
    for (int k = 0; k < NB; ++k)
#pragma unroll
        for (int i = 0; i < 10; ++i) s[k][i] = 0.f;

    // stream input rows; all indices compile-time via folds
    static_for([&](auto Rc) {
        constexpr int R = decltype(Rc)::value;
        float xr[NB][5];
#pragma unroll
        for (int k = 0; k < NB; ++k)
#pragma unroll
            for (int c = 0; c < 5; ++c)
                xr[k][c] = cval[c] ? xb[k * 1000 + R * 100 + ccol[c]] : 0.f;

        static_for([&](auto DIc) {
            constexpr int DI = decltype(DIc)::value;
            constexpr int I  = R + 2 - DI;   // output row fed by (R, DI)
            if constexpr (I >= 0 && I <= 9) {
                const float* wp = &wl[I * 1250 + jl * 25 + DI * 5];
                const float w0 = wp[0], w1 = wp[1], w2 = wp[2], w3 = wp[3], w4 = wp[4];
#pragma unroll
                for (int k = 0; k < NB; ++k) {
                    float a = s[k][I];
                    a = fmaf(xr[k][0], w0, a);
                    a = fmaf(xr[k][1], w1, a);
                    a = fmaf(xr[k][2], w2, a);
                    a = fmaf(xr[k][3], w3, a);
                    a = fmaf(xr[k][4], w4, a);
                    s[k][I] = a;
                }
            }
        }, std::make_integer_sequence<int, 5>{});
    }, std::make_integer_sequence<int, 10>{});

    // epilogue: sigmoid + forecast/penalty reductions (center x reloads are L1-hot)
    float fore[NB], pen[NB];
#pragma unroll
    for (int k = 0; k < NB; ++k) { fore[k] = 0.f; pen[k] = 0.f; }

    static_for([&](auto Ic) {
        constexpr int I = decltype(Ic)::value;
#pragma unroll
        for (int k = 0; k < NB; ++k) {
            float itm = fast_sigmoid(s[k][I]);
            float xc  = xb[k * 1000 + I * 100 + j];
            fore[k] = fmaf(xc, itm, fore[k]);
            pen[k]  = fmaf(0.01f * itm, itm, pen[k]);
        }
    }, std::make_integer_sequence<int, 10>{});

    // out[b][ch][j], b = bg*NB+k
    float* ob = out + bg * (NB * 200) + j;
#pragma unroll
    for (int k = 0; k < NB; ++k) {
        ob[k * 200]       = fore[k];
        ob[k * 200 + 100] = pen[k];
    }
}

extern "C" void kernel_launch(void* const* d_in, const int* in_sizes, int n_in,
                              void* d_out, int out_size, void* d_ws, size_t ws_size,
                              hipStream_t stream) {
    const float* x = (const float*)d_in[0];   // (16384, 10, 100) f32
    const float* w = (const float*)d_in[1];   // (10, 100, 5, 5)  f32
    float* out = (float*)d_out;               // (16384, 2, 100)  f32
    const int threads = (16384 / NB) * 100;   // 409600
    dim3 grid(threads / 256), block(256);     // 1600 blocks
    hipLaunchKernelGGL(glm_fused, grid, block, 0, stream, x, w, out);
}

// Round 4
// 161.268 us; speedup vs baseline: 2.9411x; 2.9411x over previous
//
#include <hip/hip_runtime.h>

// LocalGLMnet fused forward, v3: spill-proof by construction.
// v1/v2 post-mortem: both compiled with VGPR=84 + ~500 MB scratch traffic
// (WRITE_SIZE 438/531 MB vs 13 MB output) -> local-memory arrays, 380-470 us.
// v3 uses ONLY named scalar variables (macro-generated), explicit 10-iteration
// schedule, no lambdas/loops/arrays in the hot path, and no min-occupancy cap.
//
// Schedule: stream x rows R=0..9 (each x element loaded once). Row R feeds
// output rows I=R-2..R+2 (tap row DI=R-I+2). Output row I completes at end of
// iter R=I+2 -> finalize (sigmoid, forecast/penalty) inline using a 2-deep
// named "center" ring (no epilogue reloads). Weights: LDS half-tile
// (10*50*25 f32 = 50 KB), stride-25 dword reads = 2-way bank alias = free.

#define L2E 1.44269504088896340736f

__device__ __forceinline__ float fast_sigmoid(float s) {
    float e = __builtin_amdgcn_exp2f(s * (-L2E));   // exp(-s)
    return __builtin_amdgcn_rcpf(1.0f + e);         // 1/(1+exp(-s))
}

#define G_DECL(S) \
    float s##S##0=0.f,s##S##1=0.f,s##S##2=0.f,s##S##3=0.f,s##S##4=0.f, \
          s##S##5=0.f,s##S##6=0.f,s##S##7=0.f,s##S##8=0.f,s##S##9=0.f; \
    float f##S=0.f, p##S=0.f, cen1##S=0.f, cen2##S=0.f; \
    float xr##S##0, xr##S##1, xr##S##2, xr##S##3, xr##S##4;

#define G_LOADROW(S, R) { \
    const float* rp_ = x##S + (R) * 100; \
    xr##S##0 = v0 ? rp_[c0] : 0.f; \
    xr##S##1 = v1 ? rp_[c1] : 0.f; \
    xr##S##2 = rp_[c2]; \
    xr##S##3 = v3 ? rp_[c3] : 0.f; \
    xr##S##4 = v4 ? rp_[c4] : 0.f; }

#define G_LOADALL(R) G_LOADROW(A,R) G_LOADROW(B,R) G_LOADROW(C,R) G_LOADROW(D,R)

#define G_ACC_(S, I) \
    s##S##I = fmaf(xr##S##4, w4_, fmaf(xr##S##3, w3_, fmaf(xr##S##2, w2_, \
              fmaf(xr##S##1, w1_, fmaf(xr##S##0, w0_, s##S##I)))));
#define G_ACC(S, I) G_ACC_(S, I)

#define G_TAP(DI, I) { \
    const float* wp_ = wj + (I) * 1250 + (DI) * 5; \
    const float w0_=wp_[0], w1_=wp_[1], w2_=wp_[2], w3_=wp_[3], w4_=wp_[4]; \
    G_ACC(A, I) G_ACC(B, I) G_ACC(C, I) G_ACC(D, I) }

#define G_FIN1_(S, I, CEN) { \
    float itm_ = fast_sigmoid(s##S##I); \
    f##S = fmaf(CEN, itm_, f##S); \
    p##S = fmaf(0.01f * itm_, itm_, p##S); }
#define G_FIN1(S, I, CEN) G_FIN1_(S, I, CEN)

#define G_FINALL(I) G_FIN1(A,I,cen2A) G_FIN1(B,I,cen2B) G_FIN1(C,I,cen2C) G_FIN1(D,I,cen2D)

#define G_SHIFT(S) cen2##S = cen1##S; cen1##S = xr##S##2;
#define G_SHIFTALL() G_SHIFT(A) G_SHIFT(B) G_SHIFT(C) G_SHIFT(D)

__global__ __launch_bounds__(256)
void glm_fused(const float* __restrict__ x, const float* __restrict__ w,
               float* __restrict__ out) {
    __shared__ float wl[12500];  // [i][jl][di*5+dc], jl in [0,50) for this j-half

    const int tid = threadIdx.x;
    const int jh  = blockIdx.x & 1;   // j-half: 0 -> j 0..49, 1 -> j 50..99
    const int blk = blockIdx.x >> 1;

    // stage weight half-tile once (validated in v1/v2)
    {
        const float2* __restrict__ src = (const float2*)w;
        float2* dst = (float2*)wl;
        for (int u = tid; u < 6250; u += 256) {
            int i  = u / 625;
            int r2 = u - i * 625;
            dst[i * 625 + r2] = src[i * 1250 + jh * 625 + r2];
        }
    }
    __syncthreads();

    const int tl = blk * 256 + tid;
    const int jl = tl % 50;
    const int bg = tl / 50;           // group of 4 batches
    const int j  = jh * 50 + jl;

    const float* __restrict__ xA = x + bg * 4000;
    const float* __restrict__ xB = xA + 1000;
    const float* __restrict__ xC = xA + 2000;
    const float* __restrict__ xD = xA + 3000;
    const float* __restrict__ wj = wl + jl * 25;   // + I*1250 + DI*5

    const bool v0 = (j >= 2), v1 = (j >= 1), v3 = (j <= 98), v4 = (j <= 97);
    const int c0 = v0 ? j - 2 : 0;
    const int c1 = v1 ? j - 1 : 0;
    const int c2 = j;
    const int c3 = v3 ? j + 1 : 0;
    const int c4 = v4 ? j + 2 : 0;

    G_DECL(A) G_DECL(B) G_DECL(C) G_DECL(D)

    G_LOADALL(0) G_TAP(0,2) G_TAP(1,1) G_TAP(2,0)                               G_SHIFTALL()
    G_LOADALL(1) G_TAP(0,3) G_TAP(1,2) G_TAP(2,1) G_TAP(3,0)                    G_SHIFTALL()
    G_LOADALL(2) G_TAP(0,4) G_TAP(1,3) G_TAP(2,2) G_TAP(3,1) G_TAP(4,0) G_FINALL(0) G_SHIFTALL()
    G_LOADALL(3) G_TAP(0,5) G_TAP(1,4) G_TAP(2,3) G_TAP(3,2) G_TAP(4,1) G_FINALL(1) G_SHIFTALL()
    G_LOADALL(4) G_TAP(0,6) G_TAP(1,5) G_TAP(2,4) G_TAP(3,3) G_TAP(4,2) G_FINALL(2) G_SHIFTALL()
    G_LOADALL(5) G_TAP(0,7) G_TAP(1,6) G_TAP(2,5) G_TAP(3,4) G_TAP(4,3) G_FINALL(3) G_SHIFTALL()
    G_LOADALL(6) G_TAP(0,8) G_TAP(1,7) G_TAP(2,6) G_TAP(3,5) G_TAP(4,4) G_FINALL(4) G_SHIFTALL()
    G_LOADALL(7) G_TAP(0,9) G_TAP(1,8) G_TAP(2,7) G_TAP(3,6) G_TAP(4,5) G_FINALL(5) G_SHIFTALL()
    G_LOADALL(8)            G_TAP(1,9) G_TAP(2,8) G_TAP(3,7) G_TAP(4,6) G_FINALL(6) G_SHIFTALL()
    G_LOADALL(9)                       G_TAP(2,9) G_TAP(3,8) G_TAP(4,7) G_FINALL(7) G_SHIFTALL()
    // after final shift: cen2 = center(row 8), cen1 = center(row 9)
    G_FIN1(A,8,cen2A) G_FIN1(B,8,cen2B) G_FIN1(C,8,cen2C) G_FIN1(D,8,cen2D)
    G_FIN1(A,9,cen1A) G_FIN1(B,9,cen1B) G_FIN1(C,9,cen1C) G_FIN1(D,9,cen1D)

    // out[b][ch][j], b = bg*4+k: base = bg*800 + k*200 + ch*100 + j
    float* ob = out + bg * 800 + j;
    ob[0]   = fA;  ob[100] = pA;
    ob[200] = fB;  ob[300] = pB;
    ob[400] = fC;  ob[500] = pC;
    ob[600] = fD;  ob[700] = pD;
}

extern "C" void kernel_launch(void* const* d_in, const int* in_sizes, int n_in,
                              void* d_out, int out_size, void* d_ws, size_t ws_size,
                              hipStream_t stream) {
    const float* x = (const float*)d_in[0];   // (16384, 10, 100) f32
    const float* w = (const float*)d_in[1];   // (10, 100, 5, 5)  f32
    float* out = (float*)d_out;               // (16384, 2, 100)  f32
    dim3 grid(1600), block(256);              // (16384/4)*100 threads
    hipLaunchKernelGGL(glm_fused, grid, block, 0, stream, x, w, out);
}

// Round 7
// 132.287 us; speedup vs baseline: 3.5854x; 1.2191x over previous
//
#include <hip/hip_runtime.h>

// LocalGLMnet fused forward, v5.
// v4 result: spill fixed (WRITE 531->14.6 MB) but latency-bound: VGPR=216 ->
// 2 waves/SIMD, VALUBusy 26%, occupancy 10%, 91 us.
// v5: NB=2 batches/thread + j-quarter blocks (LDS 25 KB) -> target <=128 VGPR
// and 16-20 waves/CU; E/O double-buffer prefetch of next x row; weights in
// LDS as float4+float split (b128+b32 per tap, was 5x b32); per-column
// clamped base pointers + imm offsets (no per-load VALU); edge columns
// handled by zeroing weights at staging (clamped x reads are valid data * 0).

#define L2E 1.44269504088896340736f

__device__ __forceinline__ float fast_sigmoid(float s) {
    float e = __builtin_amdgcn_exp2f(s * (-L2E));   // exp(-s)
    return __builtin_amdgcn_rcpf(1.0f + e);         // 1/(1+exp(-s))
}

// ---- named-scalar macro machinery (nothing runtime-indexable) ----
#define P_LOAD_(P, R) \
    xA0##P = aA0[(R)*100]; xA1##P = aA1[(R)*100]; xA2##P = aA2[(R)*100]; \
    xA3##P = aA3[(R)*100]; xA4##P = aA4[(R)*100]; \
    xB0##P = aB0[(R)*100]; xB1##P = aB1[(R)*100]; xB2##P = aB2[(R)*100]; \
    xB3##P = aB3[(R)*100]; xB4##P = aB4[(R)*100];
#define P_LOAD(P, R) P_LOAD_(P, R)

#define G_TAP_(P, DI, I) { \
    const float4 w4_ = W4p[(I)*125 + (DI)]; \
    const float  we_ = W1p[(I)*125 + (DI)]; \
    sA##I = fmaf(xA4##P, we_, fmaf(xA3##P, w4_.w, fmaf(xA2##P, w4_.z, \
            fmaf(xA1##P, w4_.y, fmaf(xA0##P, w4_.x, sA##I))))); \
    sB##I = fmaf(xB4##P, we_, fmaf(xB3##P, w4_.w, fmaf(xB2##P, w4_.z, \
            fmaf(xB1##P, w4_.y, fmaf(xB0##P, w4_.x, sB##I))))); }
#define G_TAP(P, DI, I) G_TAP_(P, DI, I)

#define G_FIN_(I, CA, CB) { \
    float tA_ = fast_sigmoid(sA##I); fA = fmaf(CA, tA_, fA); pA = fmaf(0.01f*tA_, tA_, pA); \
    float tB_ = fast_sigmoid(sB##I); fB = fmaf(CB, tB_, fB); pB = fmaf(0.01f*tB_, tB_, pB); }
#define G_FIN(I, CA, CB) G_FIN_(I, CA, CB)

#define G_SH_(P) cen2A = cen1A; cen1A = xA2##P; cen2B = cen1B; cen1B = xB2##P;
#define G_SH(P) G_SH_(P)

__global__ __launch_bounds__(256)
void glm_fused(const float* __restrict__ x, const float* __restrict__ w,
               float* __restrict__ out) {
    // weight quarter-tile, split layout: idx = i*125 + jl*5 + di
    __shared__ float4 W4s[1250];   // taps c=0..3   (20 KB, 16B-aligned)
    __shared__ float  W1s[1250];   // tap  c=4      ( 5 KB)

    const int tid   = threadIdx.x;
    const int q     = blockIdx.x & 3;        // j-quarter: j in [q*25, q*25+25)
    const int jbase = q * 25;

    // ---- stage weights once, zeroing out-of-range columns (pad semantics)
    for (int e = tid; e < 1250; e += 256) {
        int i   = e / 125;
        int r   = e - i * 125;
        int jls = r / 5;
        int di  = r - jls * 5;
        int js  = jbase + jls;
        const float* wp = w + i * 2500 + js * 25 + di * 5;
        float w0 = (js >= 2) ? wp[0] : 0.f;
        float w1 = (js >= 1) ? wp[1] : 0.f;
        float w2 = wp[2];
        float w3 = (js <= 98) ? wp[3] : 0.f;
        float w4 = (js <= 97) ? wp[4] : 0.f;
        W4s[e] = make_float4(w0, w1, w2, w3);
        W1s[e] = w4;
    }
    __syncthreads();

    const int t  = (blockIdx.x >> 2) * 256 + tid;
    const int jl = t % 25;
    const int bg = t / 25;                   // group of NB=2 batches (0..8191)
    const int j  = jbase + jl;

    const float4* W4p = W4s + jl * 5;        // + I*125 + DI (imm-foldable)
    const float*  W1p = W1s + jl * 5;

    // per-column clamped base pointers; edge safety comes from zeroed weights
    const float* xA = x + bg * 2000;
    const float* xB = xA + 1000;
    const int c0 = (j >= 2) ? j - 2 : 0;
    const int c1 = (j >= 1) ? j - 1 : 0;
    const int c2 = j;
    const int c3 = (j <= 98) ? j + 1 : 99;
    const int c4 = (j <= 97) ? j + 2 : 99;
    const float* aA0 = xA + c0; const float* aA1 = xA + c1; const float* aA2 = xA + c2;
    const float* aA3 = xA + c3; const float* aA4 = xA + c4;
    const float* aB0 = xB + c0; const float* aB1 = xB + c1; const float* aB2 = xB + c2;
    const float* aB3 = xB + c3; const float* aB4 = xB + c4;

    float sA0=0.f,sA1=0.f,sA2=0.f,sA3=0.f,sA4=0.f,sA5=0.f,sA6=0.f,sA7=0.f,sA8=0.f,sA9=0.f;
    float sB0=0.f,sB1=0.f,sB2=0.f,sB3=0.f,sB4=0.f,sB5=0.f,sB6=0.f,sB7=0.f,sB8=0.f,sB9=0.f;
    float fA=0.f,pA=0.f,fB=0.f,pB=0.f;
    float cen1A=0.f,cen2A=0.f,cen1B=0.f,cen2B=0.f;
    float xA0E,xA1E,xA2E,xA3E,xA4E,xB0E,xB1E,xB2E,xB3E,xB4E;
    float xA0O,xA1O,xA2O,xA3O,xA4O,xB0O,xB1O,xB2O,xB3O,xB4O;

    // row R feeds output I = R+2-DI; finalize I=R-2 inside iteration R.
    P_LOAD(E,0)
    P_LOAD(O,1) G_TAP(E,0,2) G_TAP(E,1,1) G_TAP(E,2,0)                                        G_SH(E)
    P_LOAD(E,2) G_TAP(O,0,3) G_TAP(O,1,2) G_TAP(O,2,1) G_TAP(O,3,0)                           G_SH(O)
    P_LOAD(O,3) G_TAP(E,0,4) G_TAP(E,1,3) G_TAP(E,2,2) G_TAP(E,3,1) G_TAP(E,4,0) G_FIN(0,cen2A,cen2B) G_SH(E)
    P_LOAD(E,4) G_TAP(O,0,5) G_TAP(O,1,4) G_TAP(O,2,3) G_TAP(O,3,2) G_TAP(O,4,1) G_FIN(1,cen2A,cen2B) G_SH(O)
    P_LOAD(O,5) G_TAP(E,0,6) G_TAP(E,1,5) G_TAP(E,2,4) G_TAP(E,3,3) G_TAP(E,4,2) G_FIN(2,cen2A,cen2B) G_SH(E)
    P_LOAD(E,6) G_TAP(O,0,7) G_TAP(O,1,6) G_TAP(O,2,5) G_TAP(O,3,4) G_TAP(O,4,3) G_FIN(3,cen2A,cen2B) G_SH(O)
    P_LOAD(O,7) G_TAP(E,0,8) G_TAP(E,1,7) G_TAP(E,2,6) G_TAP(E,3,5) G_TAP(E,4,4) G_FIN(4,cen2A,cen2B) G_SH(E)
    P_LOAD(E,8) G_TAP(O,0,9) G_TAP(O,1,8) G_TAP(O,2,7) G_TAP(O,3,6) G_TAP(O,4,5) G_FIN(5,cen2A,cen2B) G_SH(O)
    P_LOAD(O,9) G_TAP(E,1,9) G_TAP(E,2,8) G_TAP(E,3,7) G_TAP(E,4,6)              G_FIN(6,cen2A,cen2B) G_SH(E)
                G_TAP(O,2,9) G_TAP(O,3,8) G_TAP(O,4,7)                           G_FIN(7,cen2A,cen2B) G_SH(O)
    // after final shift: cen2 = center(row 8), cen1 = center(row 9)
    G_FIN(8, cen2A, cen2B)
    G_FIN(9, cen1A, cen1B)

    // out[b][ch][j], b = bg*2 + k
    float* ob = out + bg * 400 + j;
    ob[0]   = fA;  ob[100] = pA;
    ob[200] = fB;  ob[300] = pB;
}

extern "C" void kernel_launch(void* const* d_in, const int* in_sizes, int n_in,
                              void* d_out, int out_size, void* d_ws, size_t ws_size,
                              hipStream_t stream) {
    const float* x = (const float*)d_in[0];   // (16384, 10, 100) f32
    const float* w = (const float*)d_in[1];   // (10, 100, 5, 5)  f32
    float* out = (float*)d_out;               // (16384, 2, 100)  f32
    // threads = (16384/2 batches) * 100 j = 819200 -> 3200 blocks of 256
    dim3 grid(3200), block(256);
    hipLaunchKernelGGL(glm_fused, grid, block, 0, stream, x, w, out);
}

// Round 9
// 129.568 us; speedup vs baseline: 3.6607x; 1.0210x over previous
//
#include <hip/hip_runtime.h>

// LocalGLMnet fused forward, v6.
// v5 result: 61 us, VGPR=68, occupancy 28%, VALUBusy 27%, no spills.
// Diagnosis: VGPR=68 is 4 over the 64-reg occupancy cliff (waves/CU halve at
// 64/128/256) -> 16-wave cap, measured 9. Address regs are the hog: 10x 64-bit
// pointers = 20 VGPRs. v6: single SGPR base + 10 unsigned 32-bit element
// offsets (R*400-byte imm folds into the 13-bit global_load offset), plus
// __launch_bounds__(256,8) to pin VGPR<=64. LDS 25 KB -> 6 blocks/CU -> 24
// waves/CU cap. E/O prefetch + split float4/float weight LDS unchanged.

#define L2E 1.44269504088896340736f

__device__ __forceinline__ float fast_sigmoid(float s) {
    float e = __builtin_amdgcn_exp2f(s * (-L2E));   // exp(-s)
    return __builtin_amdgcn_rcpf(1.0f + e);         // 1/(1+exp(-s))
}

// ---- named-scalar macro machinery (nothing runtime-indexable) ----
// Loads: one flat base pointer + 32-bit element offsets; R*100 is a
// compile-time element offset -> folds into the instruction immediate.
#define P_LOAD_(P, R) \
    xA0##P = xg[oA0 + (R)*100u]; xA1##P = xg[oA1 + (R)*100u]; \
    xA2##P = xg[oA2 + (R)*100u]; xA3##P = xg[oA3 + (R)*100u]; \
    xA4##P = xg[oA4 + (R)*100u]; \
    xB0##P = xg[oB0 + (R)*100u]; xB1##P = xg[oB1 + (R)*100u]; \
    xB2##P = xg[oB2 + (R)*100u]; xB3##P = xg[oB3 + (R)*100u]; \
    xB4##P = xg[oB4 + (R)*100u];
#define P_LOAD(P, R) P_LOAD_(P, R)

#define G_TAP_(P, DI, I) { \
    const float4 w4_ = W4p[(I)*125 + (DI)]; \
    const float  we_ = W1p[(I)*125 + (DI)]; \
    sA##I = fmaf(xA4##P, we_, fmaf(xA3##P, w4_.w, fmaf(xA2##P, w4_.z, \
            fmaf(xA1##P, w4_.y, fmaf(xA0##P, w4_.x, sA##I))))); \
    sB##I = fmaf(xB4##P, we_, fmaf(xB3##P, w4_.w, fmaf(xB2##P, w4_.z, \
            fmaf(xB1##P, w4_.y, fmaf(xB0##P, w4_.x, sB##I))))); }
#define G_TAP(P, DI, I) G_TAP_(P, DI, I)

#define G_FIN_(I, CA, CB) { \
    float tA_ = fast_sigmoid(sA##I); fA = fmaf(CA, tA_, fA); pA = fmaf(0.01f*tA_, tA_, pA); \
    float tB_ = fast_sigmoid(sB##I); fB = fmaf(CB, tB_, fB); pB = fmaf(0.01f*tB_, tB_, pB); }
#define G_FIN(I, CA, CB) G_FIN_(I, CA, CB)

#define G_SH_(P) cen2A = cen1A; cen1A = xA2##P; cen2B = cen1B; cen1B = xB2##P;
#define G_SH(P) G_SH_(P)

__global__ __launch_bounds__(256, 8)
void glm_fused(const float* __restrict__ x, const float* __restrict__ w,
               float* __restrict__ out) {
    // weight quarter-tile, split layout: idx = i*125 + jl*5 + di
    __shared__ float4 W4s[1250];   // taps c=0..3   (20 KB, 16B-aligned)
    __shared__ float  W1s[1250];   // tap  c=4      ( 5 KB)

    const int tid   = threadIdx.x;
    const int q     = blockIdx.x & 3;        // j-quarter: j in [q*25, q*25+25)
    const int jbase = q * 25;

    // ---- stage weights once, zeroing out-of-range columns (pad semantics)
    for (int e = tid; e < 1250; e += 256) {
        int i   = e / 125;
        int r   = e - i * 125;
        int jls = r / 5;
        int di  = r - jls * 5;
        int js  = jbase + jls;
        const float* wp = w + i * 2500 + js * 25 + di * 5;
        float w0 = (js >= 2) ? wp[0] : 0.f;
        float w1 = (js >= 1) ? wp[1] : 0.f;
        float w2 = wp[2];
        float w3 = (js <= 98) ? wp[3] : 0.f;
        float w4 = (js <= 97) ? wp[4] : 0.f;
        W4s[e] = make_float4(w0, w1, w2, w3);
        W1s[e] = w4;
    }
    __syncthreads();

    const int t  = (blockIdx.x >> 2) * 256 + tid;
    const int jl = t % 25;
    const int bg = t / 25;                   // group of NB=2 batches (0..8191)
    const int j  = jbase + jl;

    const float4* W4p = W4s + jl * 5;        // + I*125 + DI (imm-foldable)
    const float*  W1p = W1s + jl * 5;

    // single base + 32-bit element offsets; edge safety via zeroed weights
    const float* __restrict__ xg = x;
    const unsigned c0 = (j >= 2) ? (unsigned)(j - 2) : 0u;
    const unsigned c1 = (j >= 1) ? (unsigned)(j - 1) : 0u;
    const unsigned c2 = (unsigned)j;
    const unsigned c3 = (j <= 98) ? (unsigned)(j + 1) : 99u;
    const unsigned c4 = (j <= 97) ? (unsigned)(j + 2) : 99u;
    const unsigned bb  = (unsigned)bg * 2000u;
    const unsigned oA0 = bb + c0, oA1 = bb + c1, oA2 = bb + c2, oA3 = bb + c3, oA4 = bb + c4;
    const unsigned oB0 = oA0 + 1000u, oB1 = oA1 + 1000u, oB2 = oA2 + 1000u,
                   oB3 = oA3 + 1000u, oB4 = oA4 + 1000u;

    float sA0=0.f,sA1=0.f,sA2=0.f,sA3=0.f,sA4=0.f,sA5=0.f,sA6=0.f,sA7=0.f,sA8=0.f,sA9=0.f;
    float sB0=0.f,sB1=0.f,sB2=0.f,sB3=0.f,sB4=0.f,sB5=0.f,sB6=0.f,sB7=0.f,sB8=0.f,sB9=0.f;
    float fA=0.f,pA=0.f,fB=0.f,pB=0.f;
    float cen1A=0.f,cen2A=0.f,cen1B=0.f,cen2B=0.f;
    float xA0E,xA1E,xA2E,xA3E,xA4E,xB0E,xB1E,xB2E,xB3E,xB4E;
    float xA0O,xA1O,xA2O,xA3O,xA4O,xB0O,xB1O,xB2O,xB3O,xB4O;

    // row R feeds output I = R+2-DI; finalize I=R-2 inside iteration R.
    P_LOAD(E,0)
    P_LOAD(O,1) G_TAP(E,0,2) G_TAP(E,1,1) G_TAP(E,2,0)                                        G_SH(E)
    P_LOAD(E,2) G_TAP(O,0,3) G_TAP(O,1,2) G_TAP(O,2,1) G_TAP(O,3,0)                           G_SH(O)
    P_LOAD(O,3) G_TAP(E,0,4) G_TAP(E,1,3) G_TAP(E,2,2) G_TAP(E,3,1) G_TAP(E,4,0) G_FIN(0,cen2A,cen2B) G_SH(E)
    P_LOAD(E,4) G_TAP(O,0,5) G_TAP(O,1,4) G_TAP(O,2,3) G_TAP(O,3,2) G_TAP(O,4,1) G_FIN(1,cen2A,cen2B) G_SH(O)
    P_LOAD(O,5) G_TAP(E,0,6) G_TAP(E,1,5) G_TAP(E,2,4) G_TAP(E,3,3) G_TAP(E,4,2) G_FIN(2,cen2A,cen2B) G_SH(E)
    P_LOAD(E,6) G_TAP(O,0,7) G_TAP(O,1,6) G_TAP(O,2,5) G_TAP(O,3,4) G_TAP(O,4,3) G_FIN(3,cen2A,cen2B) G_SH(O)
    P_LOAD(O,7) G_TAP(E,0,8) G_TAP(E,1,7) G_TAP(E,2,6) G_TAP(E,3,5) G_TAP(E,4,4) G_FIN(4,cen2A,cen2B) G_SH(E)
    P_LOAD(E,8) G_TAP(O,0,9) G_TAP(O,1,8) G_TAP(O,2,7) G_TAP(O,3,6) G_TAP(O,4,5) G_FIN(5,cen2A,cen2B) G_SH(O)
    P_LOAD(O,9) G_TAP(E,1,9) G_TAP(E,2,8) G_TAP(E,3,7) G_TAP(E,4,6)              G_FIN(6,cen2A,cen2B) G_SH(E)
                G_TAP(O,2,9) G_TAP(O,3,8) G_TAP(O,4,7)                           G_FIN(7,cen2A,cen2B) G_SH(O)
    // after final shift: cen2 = center(row 8), cen1 = center(row 9)
    G_FIN(8, cen2A, cen2B)
    G_FIN(9, cen1A, cen1B)

    // out[b][ch][j], b = bg*2 + k
    float* ob = out + bg * 400 + j;
    ob[0]   = fA;  ob[100] = pA;
    ob[200] = fB;  ob[300] = pB;
}

extern "C" void kernel_launch(void* const* d_in, const int* in_sizes, int n_in,
                              void* d_out, int out_size, void* d_ws, size_t ws_size,
                              hipStream_t stream) {
    const float* x = (const float*)d_in[0];   // (16384, 10, 100) f32
    const float* w = (const float*)d_in[1];   // (10, 100, 5, 5)  f32
    float* out = (float*)d_out;               // (16384, 2, 100)  f32
    // threads = (16384/2 batches) * 100 j = 819200 -> 3200 blocks of 256
    dim3 grid(3200), block(256);
    hipLaunchKernelGGL(glm_fused, grid, block, 0, stream, x, w, out);
}